// Round 12
// baseline (4876.209 us; speedup 1.0000x reference)
//
#include <hip/hip_runtime.h>

// Problem constants (match reference)
#define N_PTS   1000000
#define C_DIM   128
#define B_DIM   8
#define Y_DIM   468
#define X_DIM   468
#define YX      (Y_DIM * X_DIM)         // 219024
#define KSPACE  (B_DIM * YX)            // 1752192 dense key space

// Scan config
#define WG   256
#define EPT  8
#define EPB  (WG * EPT)                 // 2048 elements per scan block
#define NBLK ((KSPACE + EPB - 1) / EPB) // 856

// 3-field packed scan element: [0:21) point-count, [21:42) unique-count, [42:63) multi-count
#define F_BITS 21
#define F_MASK 0x1FFFFFu
#define SINGLE_FLAG (1ull << 63)

#define PAD_BLOCKS 1024

// native vector type for nontemporal builtins (HIP's float4 is a class)
typedef float f4 __attribute__((ext_vector_type(4)));

__device__ __forceinline__ unsigned long long shfl_up_u64(unsigned long long v, int delta) {
    unsigned lo = (unsigned)v;
    unsigned hi = (unsigned)(v >> 32);
    lo = __shfl_up(lo, delta, 64);
    hi = __shfl_up(hi, delta, 64);
    return ((unsigned long long)hi << 32) | lo;
}

// ---------------------------------------------------------------- histogram + key cache
__global__ void hist_kernel(const int* __restrict__ idx, unsigned* __restrict__ cnt,
                            unsigned* __restrict__ keys, int n) {
    int i = blockIdx.x * blockDim.x + threadIdx.x;
    if (i >= n) return;
    int4 v = ((const int4*)idx)[i];          // (b, z, y, x)
    unsigned key = (unsigned)(v.x * YX + v.z * X_DIM + v.w);
    keys[i] = key;
    atomicAdd(&cnt[key], 1u);
}

// ---------------------------------------------------------------- scan pass 1: per-block exclusive scan of packed (count|unique|multi)
// pairs[k] = exclusive prefix within block, bit63 = (cnt[k]==1)
// also: done[k] = cnt[k]  (completion countdown for fused multi gather)
__global__ void scan1_kernel(const unsigned* __restrict__ cnt,
                             unsigned* __restrict__ done,
                             unsigned long long* __restrict__ pairs,
                             unsigned long long* __restrict__ bsums, int K) {
    int base = blockIdx.x * EPB + threadIdx.x * EPT;
    unsigned long long p[EPT];
    unsigned cc[EPT];
    unsigned long long run = 0;
#pragma unroll
    for (int j = 0; j < EPT; ++j) {
        int k = base + j;
        unsigned c = (k < K) ? cnt[k] : 0u;
        cc[j] = c;
        if (k < K) done[k] = c;
        unsigned long long pr = (unsigned long long)c
                              | ((unsigned long long)(c ? 1u : 0u) << F_BITS)
                              | ((unsigned long long)(c >= 2u ? 1u : 0u) << (2 * F_BITS));
        p[j] = run;                           // exclusive within thread
        run += pr;
    }
    unsigned long long tot = run;
    // inclusive wave scan of thread totals
    int lane = threadIdx.x & 63;
    unsigned long long v = tot;
#pragma unroll
    for (int d = 1; d < 64; d <<= 1) {
        unsigned long long nv = shfl_up_u64(v, d);
        if (lane >= d) v += nv;
    }
    __shared__ unsigned long long wsum[WG / 64];
    int wid = threadIdx.x >> 6;
    if (lane == 63) wsum[wid] = v;
    __syncthreads();
    unsigned long long wexcl = 0;
    for (int w = 0; w < wid; ++w) wexcl += wsum[w];
    unsigned long long texcl = wexcl + v - tot;   // exclusive across threads in block
#pragma unroll
    for (int j = 0; j < EPT; ++j) {
        int k = base + j;
        if (k < K)
            pairs[k] = (texcl + p[j]) | (cc[j] == 1u ? SINGLE_FLAG : 0ull);
    }
    if (threadIdx.x == WG - 1) bsums[blockIdx.x] = wexcl + v;  // block total
}

// ---------------------------------------------------------------- scan pass 2: exclusive scan of block sums (single block, nb <= 1024)
__global__ void scan2_kernel(unsigned long long* __restrict__ bsums, int nb) {
    int t = threadIdx.x;
    unsigned long long orig = (t < nb) ? bsums[t] : 0ull;
    unsigned long long v = orig;
    int lane = t & 63;
#pragma unroll
    for (int d = 1; d < 64; d <<= 1) {
        unsigned long long nv = shfl_up_u64(v, d);
        if (lane >= d) v += nv;
    }
    __shared__ unsigned long long ws[1024 / 64];
    int wid = t >> 6;
    if (lane == 63) ws[wid] = v;
    __syncthreads();
    unsigned long long wexcl = 0;
    for (int w = 0; w < wid; ++w) wexcl += ws[w];
    if (t < nb) bsums[t] = wexcl + v - orig;      // exclusive
    if (t == 1023) {                              // grand total -> bsums[nb]
        unsigned long long tt = 0;
        for (int w = 0; w < 1024 / 64; ++w) tt += ws[w];
        bsums[nb] = tt;
    }
}

// ---------------------------------------------------------------- heavy fused kernel: [uniq | point (+inline multi gather) | pad]
// uniq blocks: per-key counts from ADJACENT scan prefixes; sequential outI.
// point blocks: 8 points/wave (8 lanes/point, 4 f4 slots each).
//   singleton -> NT row copy to out[rank].
//   multi     -> ticket scatter (cnt), release fence, done countdown;
//                LAST finisher's 8-lane group gathers the whole bucket
//                inline (pids via agent-scope atomic loads).
// pad blocks: stream zero rows [nU, n).
__global__ void __launch_bounds__(256)
heavy_kernel(const float* __restrict__ feat, const unsigned* __restrict__ keys,
             const unsigned long long* __restrict__ pairs,
             const unsigned long long* __restrict__ bsums,
             unsigned* __restrict__ cnt, unsigned* __restrict__ done,
             unsigned* __restrict__ pids,
             float* __restrict__ outF, float* __restrict__ outI,
             int n, int K, int pointBlocks) {
    int tid  = threadIdx.x;
    int lane = tid & 63;
    int wid  = tid >> 6;
    int bid  = blockIdx.x;

    if (bid < NBLK) {
        // ---- uniq range ----
        int base = bid * EPB + tid * EPT;
        if (base >= K) return;
        unsigned long long bofs = bsums[bid];     // same scan-block for keys base..base+7
        unsigned long long P[EPT + 1];
#pragma unroll
        for (int j = 0; j < EPT; ++j) {
            int k = base + j;
            P[j] = (k < K) ? ((pairs[k] & ~SINGLE_FLAG) + bofs) : bsums[NBLK];
        }
        {
            int k = base + EPT;                   // neighbor (crosses scan-block only at tid==255)
            P[EPT] = (k < K) ? ((pairs[k] & ~SINGLE_FLAG) + bsums[k >> 11]) : bsums[NBLK];
        }
#pragma unroll
        for (int j = 0; j < EPT; ++j) {
            int k = base + j;
            if (k >= K) break;
            unsigned long long diff = P[j + 1] - P[j];   // monotonic fields: no borrow
            unsigned c = (unsigned)(diff & F_MASK);
            if (c == 0) continue;
            unsigned rank = (unsigned)((P[j] >> F_BITS) & F_MASK);
            unsigned bb  = (unsigned)k / YX;
            unsigned rem = (unsigned)k % YX;
            outI[(size_t)rank * 3 + 0] = (float)bb;
            outI[(size_t)rank * 3 + 1] = (float)(rem / X_DIM);
            outI[(size_t)rank * 3 + 2] = (float)(rem % X_DIM);
        }
    } else if (bid < NBLK + pointBlocks) {
        // ---- point range: 8 points/wave (8 lanes/point, 4 f4 slots each) ----
        int e   = lane >> 3;
        int sub = lane & 7;
        int gbase = lane & ~7;            // group leader lane
        long p = (long)(bid - NBLK) * 32 + wid * 8 + e;
        if (p >= n) return;
        unsigned key = keys[p];
        unsigned long long pr = pairs[key];
        bool single = (pr >> 63) != 0;
        unsigned long long Pcur = (pr & ~SINGLE_FLAG) + bsums[key >> 11];
        unsigned rank  = (unsigned)((Pcur >> F_BITS) & F_MASK);
        unsigned start = (unsigned)(Pcur & F_MASK);

        // -- multi bookkeeping first (fence before the NT-store volley) --
        int isLast = 0;
        if (!single && sub == 0) {
            unsigned off = atomicSub(&cnt[key], 1u) - 1u;    // slots c-1..0
            pids[start + off] = (unsigned)p;
            __threadfence();                                 // release pid store
            unsigned rem = atomicSub(&done[key], 1u) - 1u;
            isLast = (rem == 0);
        }
        isLast = __shfl(isLast, gbase, 64);

        if (isLast) {
            // recover c from adjacent scan prefixes (monotonic fields)
            unsigned c = 0;
            if (sub == 0) {
                int k1 = (int)key + 1;
                unsigned long long Pnext = (k1 < K)
                    ? ((pairs[k1] & ~SINGLE_FLAG) + bsums[k1 >> 11])
                    : bsums[NBLK];
                c = (unsigned)((Pnext - Pcur) & F_MASK);
            }
            c = (unsigned)__shfl((int)c, gbase, 64);
            // gather bucket [start, start+c) -- all pids visible (release/acquire)
            f4 a0 = (f4)(0.f), a1 = (f4)(0.f), a2 = (f4)(0.f), a3 = (f4)(0.f);
            unsigned j = start, e2 = start + c;
            for (; j + 1 < e2; j += 2) {
                unsigned p0 = __hip_atomic_load(&pids[j],     __ATOMIC_RELAXED, __HIP_MEMORY_SCOPE_AGENT);
                unsigned p1 = __hip_atomic_load(&pids[j + 1], __ATOMIC_RELAXED, __HIP_MEMORY_SCOPE_AGENT);
                const f4* s0 = (const f4*)(feat + (size_t)p0 * C_DIM);
                const f4* s1 = (const f4*)(feat + (size_t)p1 * C_DIM);
                f4 v00 = __builtin_nontemporal_load(s0 + sub);
                f4 v01 = __builtin_nontemporal_load(s0 + sub + 8);
                f4 v02 = __builtin_nontemporal_load(s0 + sub + 16);
                f4 v03 = __builtin_nontemporal_load(s0 + sub + 24);
                f4 v10 = __builtin_nontemporal_load(s1 + sub);
                f4 v11 = __builtin_nontemporal_load(s1 + sub + 8);
                f4 v12 = __builtin_nontemporal_load(s1 + sub + 16);
                f4 v13 = __builtin_nontemporal_load(s1 + sub + 24);
                a0 += v00 + v10;
                a1 += v01 + v11;
                a2 += v02 + v12;
                a3 += v03 + v13;
            }
            if (j < e2) {
                unsigned p0 = __hip_atomic_load(&pids[j], __ATOMIC_RELAXED, __HIP_MEMORY_SCOPE_AGENT);
                const f4* s0 = (const f4*)(feat + (size_t)p0 * C_DIM);
                a0 += __builtin_nontemporal_load(s0 + sub);
                a1 += __builtin_nontemporal_load(s0 + sub + 8);
                a2 += __builtin_nontemporal_load(s0 + sub + 16);
                a3 += __builtin_nontemporal_load(s0 + sub + 24);
            }
            f4* dst = (f4*)(outF + (size_t)rank * C_DIM);
            __builtin_nontemporal_store(a0, dst + sub);
            __builtin_nontemporal_store(a1, dst + sub + 8);
            __builtin_nontemporal_store(a2, dst + sub + 16);
            __builtin_nontemporal_store(a3, dst + sub + 24);
        }

        if (single) {                     // singleton: copy own row to out[rank]
            const f4* src = (const f4*)(feat + (size_t)p * C_DIM);
            f4*       dst = (f4*)(outF + (size_t)rank * C_DIM);
            f4 v0 = __builtin_nontemporal_load(src + sub);
            f4 v1 = __builtin_nontemporal_load(src + sub + 8);
            f4 v2 = __builtin_nontemporal_load(src + sub + 16);
            f4 v3 = __builtin_nontemporal_load(src + sub + 24);
            __builtin_nontemporal_store(v0, dst + sub);
            __builtin_nontemporal_store(v1, dst + sub + 8);
            __builtin_nontemporal_store(v2, dst + sub + 16);
            __builtin_nontemporal_store(v3, dst + sub + 24);
        }
    } else {
        // ---- pad range: rows [nU, n) -> zeros + (-1, 467, 467) ----
        int e   = lane >> 3;
        int sub = lane & 7;
        unsigned long long tot = bsums[NBLK];
        long nU = (long)((tot >> F_BITS) & F_MASK);
        long pb = bid - NBLK - pointBlocks;
        long base   = nU + pb * 32 + wid * 8 + e;
        long stride = (long)PAD_BLOCKS * 32;
        f4 z = (f4)(0.f);
        for (long r = base; r < n; r += stride) {
            f4* dst = (f4*)(outF + (size_t)r * C_DIM);
            __builtin_nontemporal_store(z, dst + sub);
            __builtin_nontemporal_store(z, dst + sub + 8);
            __builtin_nontemporal_store(z, dst + sub + 16);
            __builtin_nontemporal_store(z, dst + sub + 24);
            if (sub == 0) {
                outI[(size_t)r * 3 + 0] = -1.0f;
                outI[(size_t)r * 3 + 1] = 467.0f;   // (-1 % YX) // X per numpy floor-mod
                outI[(size_t)r * 3 + 2] = 467.0f;
            }
        }
    }
}

extern "C" void kernel_launch(void* const* d_in, const int* in_sizes, int n_in,
                              void* d_out, int out_size, void* d_ws, size_t ws_size,
                              hipStream_t stream) {
    const float* feat = (const float*)d_in[0];
    const int*   idx  = (const int*)d_in[1];
    const int n = in_sizes[0] / C_DIM;   // 1,000,000
    const int K = KSPACE;

    // workspace layout (256B aligned slices)
    char* ws = (char*)d_ws;
    size_t off = 0;
    auto take = [&](size_t bytes) {
        size_t cur = off;
        off = (off + bytes + 255) & ~(size_t)255;
        return cur;
    };
    size_t o_cnt    = take((size_t)K * 4);        // count per key (ticket cursor in heavy)
    size_t o_done   = take((size_t)K * 4);        // completion countdown per key
    size_t o_keys   = take((size_t)n * 4);        // cached keys per point
    size_t o_pairs  = take((size_t)K * 8);        // packed scan prefixes + singleton flag
    size_t o_bsums  = take((size_t)(NBLK + 1) * 8);
    size_t o_pids   = take((size_t)n * 4);        // point ids (multi buckets only)

    unsigned*           cnt    = (unsigned*)(ws + o_cnt);
    unsigned*           done   = (unsigned*)(ws + o_done);
    unsigned*           keys   = (unsigned*)(ws + o_keys);
    unsigned long long* pairs  = (unsigned long long*)(ws + o_pairs);
    unsigned long long* bsums  = (unsigned long long*)(ws + o_bsums);
    unsigned*           pids   = (unsigned*)(ws + o_pids);

    float* outF = (float*)d_out;
    float* outI = outF + (size_t)n * C_DIM;

    // 1. zero cnt (fill-rate)
    hipMemsetAsync(cnt, 0, (size_t)K * 4, stream);
    // 2. histogram + cache keys
    hist_kernel<<<(n + 255) / 256, 256, 0, stream>>>(idx, cnt, keys, n);
    // 3-4. two-level exclusive scan of packed (count|unique|multi); scan1 also fills done[]
    scan1_kernel<<<NBLK, WG, 0, stream>>>(cnt, done, pairs, bsums, K);
    scan2_kernel<<<1, 1024, 0, stream>>>(bsums, NBLK);
    // 5. single fused heavy pass: [uniq | point copy/scatter + inline multi gather | pad]
    {
        int pointBlocks = (n + 31) / 32;
        heavy_kernel<<<NBLK + pointBlocks + PAD_BLOCKS, 256, 0, stream>>>(
            feat, keys, pairs, bsums, cnt, done, pids, outF, outI, n, K, pointBlocks);
    }
}

// Round 13
// 323.846 us; speedup vs baseline: 15.0572x; 15.0572x over previous
//
#include <hip/hip_runtime.h>

// Problem constants (match reference)
#define N_PTS   1000000
#define C_DIM   128
#define B_DIM   8
#define Y_DIM   468
#define X_DIM   468
#define YX      (Y_DIM * X_DIM)         // 219024
#define KSPACE  (B_DIM * YX)            // 1752192 dense key space

// Scan config
#define WG   256
#define EPT  8
#define EPB  (WG * EPT)                 // 2048 elements per scan block
#define NBLK ((KSPACE + EPB - 1) / EPB) // 856

// 3-field packed scan element: [0:21) point-count, [21:42) unique-count, [42:63) multi-count
#define F_BITS 21
#define F_MASK 0x1FFFFFu
#define SINGLE_FLAG (1ull << 63)

#define PAD_BLOCKS 1024

// native vector type for nontemporal builtins (HIP's float4 is a class)
typedef float f4 __attribute__((ext_vector_type(4)));

__device__ __forceinline__ unsigned long long shfl_up_u64(unsigned long long v, int delta) {
    unsigned lo = (unsigned)v;
    unsigned hi = (unsigned)(v >> 32);
    lo = __shfl_up(lo, delta, 64);
    hi = __shfl_up(hi, delta, 64);
    return ((unsigned long long)hi << 32) | lo;
}

// ---------------------------------------------------------------- histogram + key cache + singleton pid map
__global__ void hist_kernel(const int* __restrict__ idx, unsigned* __restrict__ cnt,
                            unsigned* __restrict__ keys, unsigned* __restrict__ pkey,
                            int n) {
    int i = blockIdx.x * blockDim.x + threadIdx.x;
    if (i >= n) return;
    int4 v = ((const int4*)idx)[i];          // (b, z, y, x)
    unsigned key = (unsigned)(v.x * YX + v.z * X_DIM + v.w);
    keys[i] = key;
    pkey[key] = (unsigned)i;                 // unique writer when cnt==1 (else unused)
    atomicAdd(&cnt[key], 1u);
}

// ---------------------------------------------------------------- scan pass 1: per-block exclusive scan of packed (count|unique|multi)
// pairs[k] = exclusive prefix within block, bit63 = (cnt[k]==1)
__global__ void scan1_kernel(const unsigned* __restrict__ cnt,
                             unsigned long long* __restrict__ pairs,
                             unsigned long long* __restrict__ bsums, int K) {
    int base = blockIdx.x * EPB + threadIdx.x * EPT;
    unsigned long long p[EPT];
    unsigned cc[EPT];
    unsigned long long run = 0;
#pragma unroll
    for (int j = 0; j < EPT; ++j) {
        int k = base + j;
        unsigned c = (k < K) ? cnt[k] : 0u;
        cc[j] = c;
        unsigned long long pr = (unsigned long long)c
                              | ((unsigned long long)(c ? 1u : 0u) << F_BITS)
                              | ((unsigned long long)(c >= 2u ? 1u : 0u) << (2 * F_BITS));
        p[j] = run;                           // exclusive within thread
        run += pr;
    }
    unsigned long long tot = run;
    // inclusive wave scan of thread totals
    int lane = threadIdx.x & 63;
    unsigned long long v = tot;
#pragma unroll
    for (int d = 1; d < 64; d <<= 1) {
        unsigned long long nv = shfl_up_u64(v, d);
        if (lane >= d) v += nv;
    }
    __shared__ unsigned long long wsum[WG / 64];
    int wid = threadIdx.x >> 6;
    if (lane == 63) wsum[wid] = v;
    __syncthreads();
    unsigned long long wexcl = 0;
    for (int w = 0; w < wid; ++w) wexcl += wsum[w];
    unsigned long long texcl = wexcl + v - tot;   // exclusive across threads in block
#pragma unroll
    for (int j = 0; j < EPT; ++j) {
        int k = base + j;
        if (k < K)
            pairs[k] = (texcl + p[j]) | (cc[j] == 1u ? SINGLE_FLAG : 0ull);
    }
    if (threadIdx.x == WG - 1) bsums[blockIdx.x] = wexcl + v;  // block total
}

// ---------------------------------------------------------------- scan pass 2: exclusive scan of block sums (single block, nb <= 1024)
__global__ void scan2_kernel(unsigned long long* __restrict__ bsums, int nb) {
    int t = threadIdx.x;
    unsigned long long orig = (t < nb) ? bsums[t] : 0ull;
    unsigned long long v = orig;
    int lane = t & 63;
#pragma unroll
    for (int d = 1; d < 64; d <<= 1) {
        unsigned long long nv = shfl_up_u64(v, d);
        if (lane >= d) v += nv;
    }
    __shared__ unsigned long long ws[1024 / 64];
    int wid = t >> 6;
    if (lane == 63) ws[wid] = v;
    __syncthreads();
    unsigned long long wexcl = 0;
    for (int w = 0; w < wid; ++w) wexcl += ws[w];
    if (t < nb) bsums[t] = wexcl + v - orig;      // exclusive
    if (t == 1023) {                              // grand total -> bsums[nb]
        unsigned long long tt = 0;
        for (int w = 0; w < 1024 / 64; ++w) tt += ws[w];
        bsums[nb] = tt;
    }
}

// ---------------------------------------------------------------- heavy fused kernel: [uniq+singleton-copy | multi-pid scatter | pad]
// uniq blocks (rank-driven): sequential outI, wl for multi, and SINGLETON
//   row copy with scattered feat reads + rank-sequential out writes
//   (direction-inverted vs r10; block's ranks are a contiguous window).
// scatter blocks: 1 thread/point, multi pid ticket scatter only.
// pad blocks: stream zero rows [nU, n).
__global__ void __launch_bounds__(256)
heavy_kernel(const float* __restrict__ feat, const unsigned* __restrict__ keys,
             const unsigned* __restrict__ pkey,
             const unsigned long long* __restrict__ pairs,
             const unsigned long long* __restrict__ bsums,
             unsigned* __restrict__ cnt, unsigned* __restrict__ pids,
             uint4* __restrict__ wl,
             float* __restrict__ outF, float* __restrict__ outI,
             int n, int K, int scatBlocks) {
    int tid  = threadIdx.x;
    int bid  = blockIdx.x;

    if (bid < NBLK) {
        // ---- uniq + singleton copy range ----
        __shared__ unsigned s_pid[EPB];
        __shared__ unsigned s_rank[EPB];
        __shared__ unsigned s_cnt;
        if (tid == 0) s_cnt = 0;
        __syncthreads();

        int base = bid * EPB + tid * EPT;
        if (base < K) {
            unsigned long long bofs = bsums[bid];   // same scan-block for keys base..base+7
            unsigned long long P[EPT + 1];
#pragma unroll
            for (int j = 0; j < EPT; ++j) {
                int k = base + j;
                P[j] = (k < K) ? ((pairs[k] & ~SINGLE_FLAG) + bofs) : bsums[NBLK];
            }
            {
                int k = base + EPT;                 // neighbor (crosses scan-block only at tid==255)
                P[EPT] = (k < K) ? ((pairs[k] & ~SINGLE_FLAG) + bsums[k >> 11]) : bsums[NBLK];
            }
#pragma unroll
            for (int j = 0; j < EPT; ++j) {
                int k = base + j;
                if (k >= K) break;
                unsigned long long diff = P[j + 1] - P[j];   // monotonic fields: no borrow
                unsigned c = (unsigned)(diff & F_MASK);
                if (c == 0) continue;
                unsigned rank = (unsigned)((P[j] >> F_BITS) & F_MASK);
                unsigned bb  = (unsigned)k / YX;
                unsigned rem = (unsigned)k % YX;
                outI[(size_t)rank * 3 + 0] = (float)bb;
                outI[(size_t)rank * 3 + 1] = (float)(rem / X_DIM);
                outI[(size_t)rank * 3 + 2] = (float)(rem % X_DIM);
                if (c == 1) {                        // singleton: queue for cooperative copy
                    unsigned slot = atomicAdd(&s_cnt, 1u);
                    s_pid[slot]  = pkey[k];          // sequential pkey read (block's key window)
                    s_rank[slot] = rank;
                } else {
                    unsigned start = (unsigned)(P[j] & F_MASK);
                    unsigned mslot = (unsigned)((P[j] >> (2 * F_BITS)) & F_MASK);
                    wl[mslot] = make_uint4(start, start + c, (unsigned)k, rank);
                }
            }
        }
        __syncthreads();

        // cooperative singleton copy: 32 groups x 8 lanes; scattered reads,
        // rank-window-sequential writes; 2-entry unroll for 8 loads in flight
        unsigned m = s_cnt;
        int g   = tid >> 3;                  // group 0..31
        int sub = tid & 7;                   // f4 slots sub, sub+8, sub+16, sub+24
        unsigned i = g;
        for (; i + 32 < m; i += 64) {
            unsigned pid0 = s_pid[i],      rk0 = s_rank[i];
            unsigned pid1 = s_pid[i + 32], rk1 = s_rank[i + 32];
            const f4* s0 = (const f4*)(feat + (size_t)pid0 * C_DIM);
            const f4* s1 = (const f4*)(feat + (size_t)pid1 * C_DIM);
            f4 v00 = __builtin_nontemporal_load(s0 + sub);
            f4 v01 = __builtin_nontemporal_load(s0 + sub + 8);
            f4 v02 = __builtin_nontemporal_load(s0 + sub + 16);
            f4 v03 = __builtin_nontemporal_load(s0 + sub + 24);
            f4 v10 = __builtin_nontemporal_load(s1 + sub);
            f4 v11 = __builtin_nontemporal_load(s1 + sub + 8);
            f4 v12 = __builtin_nontemporal_load(s1 + sub + 16);
            f4 v13 = __builtin_nontemporal_load(s1 + sub + 24);
            f4* d0 = (f4*)(outF + (size_t)rk0 * C_DIM);
            f4* d1 = (f4*)(outF + (size_t)rk1 * C_DIM);
            __builtin_nontemporal_store(v00, d0 + sub);
            __builtin_nontemporal_store(v01, d0 + sub + 8);
            __builtin_nontemporal_store(v02, d0 + sub + 16);
            __builtin_nontemporal_store(v03, d0 + sub + 24);
            __builtin_nontemporal_store(v10, d1 + sub);
            __builtin_nontemporal_store(v11, d1 + sub + 8);
            __builtin_nontemporal_store(v12, d1 + sub + 16);
            __builtin_nontemporal_store(v13, d1 + sub + 24);
        }
        for (; i < m; i += 32) {
            unsigned pid0 = s_pid[i], rk0 = s_rank[i];
            const f4* s0 = (const f4*)(feat + (size_t)pid0 * C_DIM);
            f4 v00 = __builtin_nontemporal_load(s0 + sub);
            f4 v01 = __builtin_nontemporal_load(s0 + sub + 8);
            f4 v02 = __builtin_nontemporal_load(s0 + sub + 16);
            f4 v03 = __builtin_nontemporal_load(s0 + sub + 24);
            f4* d0 = (f4*)(outF + (size_t)rk0 * C_DIM);
            __builtin_nontemporal_store(v00, d0 + sub);
            __builtin_nontemporal_store(v01, d0 + sub + 8);
            __builtin_nontemporal_store(v02, d0 + sub + 16);
            __builtin_nontemporal_store(v03, d0 + sub + 24);
        }
    } else if (bid < NBLK + scatBlocks) {
        // ---- scatter range: 1 thread/point, multi pids only ----
        long p = (long)(bid - NBLK) * 256 + tid;
        if (p >= n) return;
        unsigned key = keys[p];
        unsigned long long pr = pairs[key];
        if (!(pr >> 63)) {                   // multi: ticket scatter (cnt as cursor)
            unsigned start = (unsigned)((pr + bsums[key >> 11]) & F_MASK);
            unsigned off = atomicSub(&cnt[key], 1u) - 1u;    // c-1, ..., 0
            pids[start + off] = (unsigned)p;
        }
    } else {
        // ---- pad range: rows [nU, n) -> zeros + (-1, 467, 467) ----
        int lane = tid & 63;
        int wid  = tid >> 6;
        int e    = lane >> 3;
        int sub  = lane & 7;
        unsigned long long tot = bsums[NBLK];
        long nU = (long)((tot >> F_BITS) & F_MASK);
        long pb = bid - NBLK - scatBlocks;
        long base   = nU + pb * 32 + wid * 8 + e;
        long stride = (long)PAD_BLOCKS * 32;
        f4 z = (f4)(0.f);
        for (long r = base; r < n; r += stride) {
            f4* dst = (f4*)(outF + (size_t)r * C_DIM);
            __builtin_nontemporal_store(z, dst + sub);
            __builtin_nontemporal_store(z, dst + sub + 8);
            __builtin_nontemporal_store(z, dst + sub + 16);
            __builtin_nontemporal_store(z, dst + sub + 24);
            if (sub == 0) {
                outI[(size_t)r * 3 + 0] = -1.0f;
                outI[(size_t)r * 3 + 1] = 467.0f;   // (-1 % YX) // X per numpy floor-mod
                outI[(size_t)r * 3 + 2] = 467.0f;
            }
        }
    }
}

// ---------------------------------------------------------------- multi gather+sum: 4 rows/wave, paired-pid unroll (r10-exact)
__global__ void __launch_bounds__(256)
multi_kernel(const float* __restrict__ feat, const unsigned* __restrict__ pointIds,
             const uint4* __restrict__ wl,
             const unsigned long long* __restrict__ total,
             float* __restrict__ outF) {
    int lane = threadIdx.x & 63;
    int wid  = threadIdx.x >> 6;
    int rq   = lane >> 4;                 // row within wave's 4
    int sub  = lane & 15;                 // f4 slots sub, sub+16
    long m = (long)(((*total) >> (2 * F_BITS)) & F_MASK);
    long base   = (long)blockIdx.x * 16 + wid * 4 + rq;
    long stride = (long)gridDim.x * 16;
    for (long r = base; r < m; r += stride) {
        uint4 d = wl[r];
        f4 a0 = (f4)(0.f);
        f4 a1 = (f4)(0.f);
        unsigned j = d.x, e = d.y;
        for (; j + 1 < e; j += 2) {       // paired: 4 independent row-half loads in flight
            unsigned p0 = pointIds[j];
            unsigned p1 = pointIds[j + 1];
            const f4* s0 = (const f4*)(feat + (size_t)p0 * C_DIM);
            const f4* s1 = (const f4*)(feat + (size_t)p1 * C_DIM);
            f4 v00 = __builtin_nontemporal_load(s0 + sub);
            f4 v01 = __builtin_nontemporal_load(s0 + sub + 16);
            f4 v10 = __builtin_nontemporal_load(s1 + sub);
            f4 v11 = __builtin_nontemporal_load(s1 + sub + 16);
            a0 += v00 + v10;
            a1 += v01 + v11;
        }
        if (j < e) {
            unsigned p0 = pointIds[j];
            const f4* s0 = (const f4*)(feat + (size_t)p0 * C_DIM);
            f4 v00 = __builtin_nontemporal_load(s0 + sub);
            f4 v01 = __builtin_nontemporal_load(s0 + sub + 16);
            a0 += v00;
            a1 += v01;
        }
        f4* dst = (f4*)(outF + (size_t)d.w * C_DIM);
        __builtin_nontemporal_store(a0, dst + sub);
        __builtin_nontemporal_store(a1, dst + sub + 16);
    }
}

extern "C" void kernel_launch(void* const* d_in, const int* in_sizes, int n_in,
                              void* d_out, int out_size, void* d_ws, size_t ws_size,
                              hipStream_t stream) {
    const float* feat = (const float*)d_in[0];
    const int*   idx  = (const int*)d_in[1];
    const int n = in_sizes[0] / C_DIM;   // 1,000,000
    const int K = KSPACE;

    // workspace layout (256B aligned slices)
    char* ws = (char*)d_ws;
    size_t off = 0;
    auto take = [&](size_t bytes) {
        size_t cur = off;
        off = (off + bytes + 255) & ~(size_t)255;
        return cur;
    };
    size_t o_cnt    = take((size_t)K * 4);        // count per key (reused as scatter cursor)
    size_t o_pkey   = take((size_t)K * 4);        // pid per key (valid for singletons)
    size_t o_keys   = take((size_t)n * 4);        // cached keys per point
    size_t o_pairs  = take((size_t)K * 8);        // packed scan prefixes + singleton flag
    size_t o_bsums  = take((size_t)(NBLK + 1) * 8);
    size_t o_pids   = take((size_t)n * 4);        // point ids (multi buckets only)
    size_t o_wl     = take((size_t)(n / 2 + 1) * 16);  // worklist {start,end,key,rank}

    unsigned*           cnt    = (unsigned*)(ws + o_cnt);
    unsigned*           pkey   = (unsigned*)(ws + o_pkey);
    unsigned*           keys   = (unsigned*)(ws + o_keys);
    unsigned long long* pairs  = (unsigned long long*)(ws + o_pairs);
    unsigned long long* bsums  = (unsigned long long*)(ws + o_bsums);
    unsigned*           pids   = (unsigned*)(ws + o_pids);
    uint4*              wl     = (uint4*)(ws + o_wl);

    float* outF = (float*)d_out;
    float* outI = outF + (size_t)n * C_DIM;

    // 1. zero cnt (fill-rate)
    hipMemsetAsync(cnt, 0, (size_t)K * 4, stream);
    // 2. histogram + key cache + singleton pid map
    hist_kernel<<<(n + 255) / 256, 256, 0, stream>>>(idx, cnt, keys, pkey, n);
    // 3-4. two-level exclusive scan of packed (count|unique|multi)
    scan1_kernel<<<NBLK, WG, 0, stream>>>(cnt, pairs, bsums, K);
    scan2_kernel<<<1, 1024, 0, stream>>>(bsums, NBLK);
    // 5. fused heavy pass: [uniq + rank-sequential singleton copy | multi-pid scatter | pad]
    {
        int scatBlocks = (n + 255) / 256;
        heavy_kernel<<<NBLK + scatBlocks + PAD_BLOCKS, 256, 0, stream>>>(
            feat, keys, pkey, pairs, bsums, cnt, pids, wl, outF, outI, n, K, scatBlocks);
    }
    // 6. multi gather+sum (r10-exact geometry)
    multi_kernel<<<4096, 256, 0, stream>>>(feat, pids, wl, bsums + NBLK, outF);
}

// Round 14
// 310.465 us; speedup vs baseline: 15.7061x; 1.0431x over previous
//
#include <hip/hip_runtime.h>

// Problem constants (match reference)
#define N_PTS   1000000
#define C_DIM   128
#define B_DIM   8
#define Y_DIM   468
#define X_DIM   468
#define YX      (Y_DIM * X_DIM)         // 219024
#define KSPACE  (B_DIM * YX)            // 1752192 dense key space

// Scan config
#define WG   256
#define EPT  8
#define EPB  (WG * EPT)                 // 2048 elements per scan block
#define NBLK ((KSPACE + EPB - 1) / EPB) // 856

// 3-field packed scan element: [0:21) point-count, [21:42) unique-count, [42:63) multi-count
#define F_BITS 21
#define F_MASK 0x1FFFFFu
#define SINGLE_FLAG (1ull << 63)

#define MULTI_BLOCKS 4096
#define PAD_BLOCKS   1024

// native vector type for nontemporal builtins (HIP's float4 is a class)
typedef float f4 __attribute__((ext_vector_type(4)));

__device__ __forceinline__ unsigned long long shfl_up_u64(unsigned long long v, int delta) {
    unsigned lo = (unsigned)v;
    unsigned hi = (unsigned)(v >> 32);
    lo = __shfl_up(lo, delta, 64);
    hi = __shfl_up(hi, delta, 64);
    return ((unsigned long long)hi << 32) | lo;
}

// ---------------------------------------------------------------- histogram + key cache
__global__ void hist_kernel(const int* __restrict__ idx, unsigned* __restrict__ cnt,
                            unsigned* __restrict__ keys, int n) {
    int i = blockIdx.x * blockDim.x + threadIdx.x;
    if (i >= n) return;
    int4 v = ((const int4*)idx)[i];          // (b, z, y, x)
    unsigned key = (unsigned)(v.x * YX + v.z * X_DIM + v.w);
    keys[i] = key;
    atomicAdd(&cnt[key], 1u);
}

// ---------------------------------------------------------------- scan pass 1: per-block exclusive scan of packed (count|unique|multi)
// pairs[k] = exclusive prefix within block, bit63 = (cnt[k]==1)
__global__ void scan1_kernel(const unsigned* __restrict__ cnt,
                             unsigned long long* __restrict__ pairs,
                             unsigned long long* __restrict__ bsums, int K) {
    int base = blockIdx.x * EPB + threadIdx.x * EPT;
    unsigned long long p[EPT];
    unsigned cc[EPT];
    unsigned long long run = 0;
#pragma unroll
    for (int j = 0; j < EPT; ++j) {
        int k = base + j;
        unsigned c = (k < K) ? cnt[k] : 0u;
        cc[j] = c;
        unsigned long long pr = (unsigned long long)c
                              | ((unsigned long long)(c ? 1u : 0u) << F_BITS)
                              | ((unsigned long long)(c >= 2u ? 1u : 0u) << (2 * F_BITS));
        p[j] = run;                           // exclusive within thread
        run += pr;
    }
    unsigned long long tot = run;
    // inclusive wave scan of thread totals
    int lane = threadIdx.x & 63;
    unsigned long long v = tot;
#pragma unroll
    for (int d = 1; d < 64; d <<= 1) {
        unsigned long long nv = shfl_up_u64(v, d);
        if (lane >= d) v += nv;
    }
    __shared__ unsigned long long wsum[WG / 64];
    int wid = threadIdx.x >> 6;
    if (lane == 63) wsum[wid] = v;
    __syncthreads();
    unsigned long long wexcl = 0;
    for (int w = 0; w < wid; ++w) wexcl += wsum[w];
    unsigned long long texcl = wexcl + v - tot;   // exclusive across threads in block
#pragma unroll
    for (int j = 0; j < EPT; ++j) {
        int k = base + j;
        if (k < K)
            pairs[k] = (texcl + p[j]) | (cc[j] == 1u ? SINGLE_FLAG : 0ull);
    }
    if (threadIdx.x == WG - 1) bsums[blockIdx.x] = wexcl + v;  // block total
}

// ---------------------------------------------------------------- scan pass 2: exclusive scan of block sums (single block, nb <= 1024)
__global__ void scan2_kernel(unsigned long long* __restrict__ bsums, int nb) {
    int t = threadIdx.x;
    unsigned long long orig = (t < nb) ? bsums[t] : 0ull;
    unsigned long long v = orig;
    int lane = t & 63;
#pragma unroll
    for (int d = 1; d < 64; d <<= 1) {
        unsigned long long nv = shfl_up_u64(v, d);
        if (lane >= d) v += nv;
    }
    __shared__ unsigned long long ws[1024 / 64];
    int wid = t >> 6;
    if (lane == 63) ws[wid] = v;
    __syncthreads();
    unsigned long long wexcl = 0;
    for (int w = 0; w < wid; ++w) wexcl += ws[w];
    if (t < nb) bsums[t] = wexcl + v - orig;      // exclusive
    if (t == 1023) {                              // grand total -> bsums[nb]
        unsigned long long tt = 0;
        for (int w = 0; w < 1024 / 64; ++w) tt += ws[w];
        bsums[nb] = tt;
    }
}

// ---------------------------------------------------------------- meta2: [uniq | per-point resolve]
// uniq blocks: per-key counts from ADJACENT scan prefixes; sequential outI
//   writes + multi worklist (deterministic slots).
// resolve blocks: 1 thread/point: one random pairs[key] lookup; multi ->
//   pid ticket scatter; all -> prank[i] = rank | (single<<31) sequential.
__global__ void __launch_bounds__(256)
meta2_kernel(const unsigned* __restrict__ keys,
             const unsigned long long* __restrict__ pairs,
             const unsigned long long* __restrict__ bsums,
             unsigned* __restrict__ cnt, unsigned* __restrict__ pids,
             unsigned* __restrict__ prank, uint4* __restrict__ wl,
             float* __restrict__ outI, int n, int K) {
    int tid = threadIdx.x;
    int bid = blockIdx.x;

    if (bid < NBLK) {
        // ---- uniq range ----
        int base = bid * EPB + tid * EPT;
        if (base >= K) return;
        unsigned long long bofs = bsums[bid];     // same scan-block for keys base..base+7
        unsigned long long P[EPT + 1];
#pragma unroll
        for (int j = 0; j < EPT; ++j) {
            int k = base + j;
            P[j] = (k < K) ? ((pairs[k] & ~SINGLE_FLAG) + bofs) : bsums[NBLK];
        }
        {
            int k = base + EPT;                   // neighbor (crosses scan-block only at tid==255)
            P[EPT] = (k < K) ? ((pairs[k] & ~SINGLE_FLAG) + bsums[k >> 11]) : bsums[NBLK];
        }
#pragma unroll
        for (int j = 0; j < EPT; ++j) {
            int k = base + j;
            if (k >= K) break;
            unsigned long long diff = P[j + 1] - P[j];   // monotonic fields: no borrow
            unsigned c = (unsigned)(diff & F_MASK);
            if (c == 0) continue;
            unsigned rank = (unsigned)((P[j] >> F_BITS) & F_MASK);
            unsigned bb  = (unsigned)k / YX;
            unsigned rem = (unsigned)k % YX;
            outI[(size_t)rank * 3 + 0] = (float)bb;
            outI[(size_t)rank * 3 + 1] = (float)(rem / X_DIM);
            outI[(size_t)rank * 3 + 2] = (float)(rem % X_DIM);
            if (c >= 2) {
                unsigned start = (unsigned)(P[j] & F_MASK);
                unsigned mslot = (unsigned)((P[j] >> (2 * F_BITS)) & F_MASK);
                wl[mslot] = make_uint4(start, start + c, (unsigned)k, rank);
            }
        }
    } else {
        // ---- resolve range: 1 thread/point ----
        long p = (long)(bid - NBLK) * 256 + tid;
        if (p >= n) return;
        unsigned key = keys[p];
        unsigned long long pr = pairs[key];
        unsigned long long Pc = (pr & ~SINGLE_FLAG) + bsums[key >> 11];
        unsigned rank = (unsigned)((Pc >> F_BITS) & F_MASK);
        if (pr >> 63) {
            prank[p] = rank | 0x80000000u;           // singleton
        } else {
            prank[p] = rank;                          // (unused by copy)
            unsigned start = (unsigned)(Pc & F_MASK);
            unsigned off = atomicSub(&cnt[key], 1u) - 1u;    // c-1, ..., 0
            pids[start + off] = (unsigned)p;
        }
    }
}

// ---------------------------------------------------------------- copy kernel: [singleton copy | multi gather | pad]
// singleton blocks: 8 pts/wave (8 lanes/point, 4 f4 slots); chain is
//   prank (sequential) -> feat (sequential) -> out (scattered). No random load.
// multi blocks: grid-stride over wl; 4 rows/wave, paired-pid unroll.
// pad blocks: stream zero rows [nU, n).
__global__ void __launch_bounds__(256)
copy_kernel(const float* __restrict__ feat, const unsigned* __restrict__ prank,
            const unsigned* __restrict__ pointIds, const uint4* __restrict__ wl,
            const unsigned long long* __restrict__ total,
            float* __restrict__ outF, float* __restrict__ outI,
            int n, int pointBlocks) {
    int tid  = threadIdx.x;
    int lane = tid & 63;
    int wid  = tid >> 6;
    int bid  = blockIdx.x;

    if (bid < pointBlocks) {
        // ---- singleton copy: 8 points/wave ----
        int e   = lane >> 3;
        int sub = lane & 7;
        long p = (long)bid * 32 + wid * 8 + e;
        if (p >= n) return;
        unsigned pr = prank[p];
        if (!(pr >> 31)) return;              // not a singleton
        unsigned rank = pr & 0x7FFFFFFFu;
        const f4* src = (const f4*)(feat + (size_t)p * C_DIM);
        f4*       dst = (f4*)(outF + (size_t)rank * C_DIM);
        f4 v0 = __builtin_nontemporal_load(src + sub);
        f4 v1 = __builtin_nontemporal_load(src + sub + 8);
        f4 v2 = __builtin_nontemporal_load(src + sub + 16);
        f4 v3 = __builtin_nontemporal_load(src + sub + 24);
        __builtin_nontemporal_store(v0, dst + sub);
        __builtin_nontemporal_store(v1, dst + sub + 8);
        __builtin_nontemporal_store(v2, dst + sub + 16);
        __builtin_nontemporal_store(v3, dst + sub + 24);
    } else if (bid < pointBlocks + MULTI_BLOCKS) {
        // ---- multi gather: 4 rows/wave, 16 lanes/row, 2 f4 slots ----
        int rq  = lane >> 4;
        int sub = lane & 15;
        long m = (long)(((*total) >> (2 * F_BITS)) & F_MASK);
        long base   = (long)(bid - pointBlocks) * 16 + wid * 4 + rq;
        long stride = (long)MULTI_BLOCKS * 16;
        for (long r = base; r < m; r += stride) {
            uint4 d = wl[r];
            f4 a0 = (f4)(0.f);
            f4 a1 = (f4)(0.f);
            unsigned j = d.x, e2 = d.y;
            for (; j + 1 < e2; j += 2) {      // paired: 4 independent row-half loads in flight
                unsigned p0 = pointIds[j];
                unsigned p1 = pointIds[j + 1];
                const f4* s0 = (const f4*)(feat + (size_t)p0 * C_DIM);
                const f4* s1 = (const f4*)(feat + (size_t)p1 * C_DIM);
                f4 v00 = __builtin_nontemporal_load(s0 + sub);
                f4 v01 = __builtin_nontemporal_load(s0 + sub + 16);
                f4 v10 = __builtin_nontemporal_load(s1 + sub);
                f4 v11 = __builtin_nontemporal_load(s1 + sub + 16);
                a0 += v00 + v10;
                a1 += v01 + v11;
            }
            if (j < e2) {
                unsigned p0 = pointIds[j];
                const f4* s0 = (const f4*)(feat + (size_t)p0 * C_DIM);
                f4 v00 = __builtin_nontemporal_load(s0 + sub);
                f4 v01 = __builtin_nontemporal_load(s0 + sub + 16);
                a0 += v00;
                a1 += v01;
            }
            f4* dst = (f4*)(outF + (size_t)d.w * C_DIM);
            __builtin_nontemporal_store(a0, dst + sub);
            __builtin_nontemporal_store(a1, dst + sub + 16);
        }
    } else {
        // ---- pad range: rows [nU, n) -> zeros + (-1, 467, 467) ----
        int e   = lane >> 3;
        int sub = lane & 7;
        unsigned long long tot = *total;
        long nU = (long)((tot >> F_BITS) & F_MASK);
        long pb = bid - pointBlocks - MULTI_BLOCKS;
        long base   = nU + pb * 32 + wid * 8 + e;
        long stride = (long)PAD_BLOCKS * 32;
        f4 z = (f4)(0.f);
        for (long r = base; r < n; r += stride) {
            f4* dst = (f4*)(outF + (size_t)r * C_DIM);
            __builtin_nontemporal_store(z, dst + sub);
            __builtin_nontemporal_store(z, dst + sub + 8);
            __builtin_nontemporal_store(z, dst + sub + 16);
            __builtin_nontemporal_store(z, dst + sub + 24);
            if (sub == 0) {
                outI[(size_t)r * 3 + 0] = -1.0f;
                outI[(size_t)r * 3 + 1] = 467.0f;   // (-1 % YX) // X per numpy floor-mod
                outI[(size_t)r * 3 + 2] = 467.0f;
            }
        }
    }
}

extern "C" void kernel_launch(void* const* d_in, const int* in_sizes, int n_in,
                              void* d_out, int out_size, void* d_ws, size_t ws_size,
                              hipStream_t stream) {
    const float* feat = (const float*)d_in[0];
    const int*   idx  = (const int*)d_in[1];
    const int n = in_sizes[0] / C_DIM;   // 1,000,000
    const int K = KSPACE;

    // workspace layout (256B aligned slices)
    char* ws = (char*)d_ws;
    size_t off = 0;
    auto take = [&](size_t bytes) {
        size_t cur = off;
        off = (off + bytes + 255) & ~(size_t)255;
        return cur;
    };
    size_t o_cnt    = take((size_t)K * 4);        // count per key (reused as scatter cursor)
    size_t o_keys   = take((size_t)n * 4);        // cached keys per point
    size_t o_prank  = take((size_t)n * 4);        // per-point rank | single<<31
    size_t o_pairs  = take((size_t)K * 8);        // packed scan prefixes + singleton flag
    size_t o_bsums  = take((size_t)(NBLK + 1) * 8);
    size_t o_pids   = take((size_t)n * 4);        // point ids (multi buckets only)
    size_t o_wl     = take((size_t)(n / 2 + 1) * 16);  // worklist {start,end,key,rank}

    unsigned*           cnt    = (unsigned*)(ws + o_cnt);
    unsigned*           keys   = (unsigned*)(ws + o_keys);
    unsigned*           prank  = (unsigned*)(ws + o_prank);
    unsigned long long* pairs  = (unsigned long long*)(ws + o_pairs);
    unsigned long long* bsums  = (unsigned long long*)(ws + o_bsums);
    unsigned*           pids   = (unsigned*)(ws + o_pids);
    uint4*              wl     = (uint4*)(ws + o_wl);

    float* outF = (float*)d_out;
    float* outI = outF + (size_t)n * C_DIM;

    // 1. zero cnt (fill-rate)
    hipMemsetAsync(cnt, 0, (size_t)K * 4, stream);
    // 2. histogram + key cache
    hist_kernel<<<(n + 255) / 256, 256, 0, stream>>>(idx, cnt, keys, n);
    // 3-4. two-level exclusive scan of packed (count|unique|multi)
    scan1_kernel<<<NBLK, WG, 0, stream>>>(cnt, pairs, bsums, K);
    scan2_kernel<<<1, 1024, 0, stream>>>(bsums, NBLK);
    // 5. meta2: [uniq (outI + wl) | per-point resolve (prank + pid scatter)]
    {
        int resolveBlocks = (n + 255) / 256;
        meta2_kernel<<<NBLK + resolveBlocks, 256, 0, stream>>>(
            keys, pairs, bsums, cnt, pids, prank, wl, outI, n, K);
    }
    // 6. copy: [singleton copy | multi gather | pad] — one wide kernel
    {
        int pointBlocks = (n + 31) / 32;
        copy_kernel<<<pointBlocks + MULTI_BLOCKS + PAD_BLOCKS, 256, 0, stream>>>(
            feat, prank, pids, wl, bsums + NBLK, outF, outI, n, pointBlocks);
    }
}

// Round 15
// 281.885 us; speedup vs baseline: 17.2986x; 1.1014x over previous
//
#include <hip/hip_runtime.h>

// Problem constants (match reference)
#define N_PTS   1000000
#define C_DIM   128
#define B_DIM   8
#define Y_DIM   468
#define X_DIM   468
#define YX      (Y_DIM * X_DIM)         // 219024
#define KSPACE  (B_DIM * YX)            // 1752192 dense key space

// Scan config
#define WG   256
#define EPT  8
#define EPB  (WG * EPT)                 // 2048 elements per scan block
#define NBLK ((KSPACE + EPB - 1) / EPB) // 856

// 3-field packed scan element: [0:21) point-count, [21:42) unique-count, [42:63) multi-count
#define F_BITS 21
#define F_MASK 0x1FFFFFu
#define SINGLE_FLAG (1ull << 63)

#define PAD_BLOCKS 2048

// native vector type for nontemporal builtins (HIP's float4 is a class)
typedef float f4 __attribute__((ext_vector_type(4)));

__device__ __forceinline__ unsigned long long shfl_up_u64(unsigned long long v, int delta) {
    unsigned lo = (unsigned)v;
    unsigned hi = (unsigned)(v >> 32);
    lo = __shfl_up(lo, delta, 64);
    hi = __shfl_up(hi, delta, 64);
    return ((unsigned long long)hi << 32) | lo;
}

// ---------------------------------------------------------------- histogram + key cache
__global__ void hist_kernel(const int* __restrict__ idx, unsigned* __restrict__ cnt,
                            unsigned* __restrict__ keys, int n) {
    int i = blockIdx.x * blockDim.x + threadIdx.x;
    if (i >= n) return;
    int4 v = ((const int4*)idx)[i];          // (b, z, y, x)
    unsigned key = (unsigned)(v.x * YX + v.z * X_DIM + v.w);
    keys[i] = key;
    atomicAdd(&cnt[key], 1u);
}

// ---------------------------------------------------------------- scan pass 1: per-block exclusive scan of packed (count|unique|multi)
// pairs[k] = exclusive prefix within block, bit63 = (cnt[k]==1)
__global__ void scan1_kernel(const unsigned* __restrict__ cnt,
                             unsigned long long* __restrict__ pairs,
                             unsigned long long* __restrict__ bsums, int K) {
    int base = blockIdx.x * EPB + threadIdx.x * EPT;
    unsigned long long p[EPT];
    unsigned cc[EPT];
    unsigned long long run = 0;
#pragma unroll
    for (int j = 0; j < EPT; ++j) {
        int k = base + j;
        unsigned c = (k < K) ? cnt[k] : 0u;
        cc[j] = c;
        unsigned long long pr = (unsigned long long)c
                              | ((unsigned long long)(c ? 1u : 0u) << F_BITS)
                              | ((unsigned long long)(c >= 2u ? 1u : 0u) << (2 * F_BITS));
        p[j] = run;                           // exclusive within thread
        run += pr;
    }
    unsigned long long tot = run;
    // inclusive wave scan of thread totals
    int lane = threadIdx.x & 63;
    unsigned long long v = tot;
#pragma unroll
    for (int d = 1; d < 64; d <<= 1) {
        unsigned long long nv = shfl_up_u64(v, d);
        if (lane >= d) v += nv;
    }
    __shared__ unsigned long long wsum[WG / 64];
    int wid = threadIdx.x >> 6;
    if (lane == 63) wsum[wid] = v;
    __syncthreads();
    unsigned long long wexcl = 0;
    for (int w = 0; w < wid; ++w) wexcl += wsum[w];
    unsigned long long texcl = wexcl + v - tot;   // exclusive across threads in block
#pragma unroll
    for (int j = 0; j < EPT; ++j) {
        int k = base + j;
        if (k < K)
            pairs[k] = (texcl + p[j]) | (cc[j] == 1u ? SINGLE_FLAG : 0ull);
    }
    if (threadIdx.x == WG - 1) bsums[blockIdx.x] = wexcl + v;  // block total
}

// ---------------------------------------------------------------- scan pass 2: exclusive scan of block sums (single block, nb <= 1024)
__global__ void scan2_kernel(unsigned long long* __restrict__ bsums, int nb) {
    int t = threadIdx.x;
    unsigned long long orig = (t < nb) ? bsums[t] : 0ull;
    unsigned long long v = orig;
    int lane = t & 63;
#pragma unroll
    for (int d = 1; d < 64; d <<= 1) {
        unsigned long long nv = shfl_up_u64(v, d);
        if (lane >= d) v += nv;
    }
    __shared__ unsigned long long ws[1024 / 64];
    int wid = t >> 6;
    if (lane == 63) ws[wid] = v;
    __syncthreads();
    unsigned long long wexcl = 0;
    for (int w = 0; w < wid; ++w) wexcl += ws[w];
    if (t < nb) bsums[t] = wexcl + v - orig;      // exclusive
    if (t == 1023) {                              // grand total -> bsums[nb]
        unsigned long long tt = 0;
        for (int w = 0; w < 1024 / 64; ++w) tt += ws[w];
        bsums[nb] = tt;
    }
}

// ---------------------------------------------------------------- per-key pass (sorted): sequential outI for all unique keys,
// multi worklist, and COMPACT rank32[k] = rank | single<<31 (7 MB table --
// halves the random-lookup line traffic in the copy pass vs 14 MB pairs)
__global__ void uniq_kernel(const unsigned* __restrict__ cnt,
                            const unsigned long long* __restrict__ pairs,
                            const unsigned long long* __restrict__ bsums,
                            uint4* __restrict__ wl, unsigned* __restrict__ rank32,
                            float* __restrict__ outI, int K) {
    int k = blockIdx.x * blockDim.x + threadIdx.x;
    if (k >= K) return;
    unsigned c = cnt[k];
    if (c == 0) return;
    unsigned long long pr = (pairs[k] & ~SINGLE_FLAG) + bsums[k >> 11];  // EPB=2048
    unsigned rank = (unsigned)((pr >> F_BITS) & F_MASK);
    rank32[k] = rank | (c == 1u ? 0x80000000u : 0u);
    // sequential-in-rank index write (ranks ascend with k)
    unsigned bb  = (unsigned)k / YX;
    unsigned rem = (unsigned)k % YX;
    outI[(size_t)rank * 3 + 0] = (float)bb;
    outI[(size_t)rank * 3 + 1] = (float)(rem / X_DIM);
    outI[(size_t)rank * 3 + 2] = (float)(rem % X_DIM);
    if (c >= 2) {
        unsigned start = (unsigned)(pr & F_MASK);
        unsigned mslot = (unsigned)((pr >> (2 * F_BITS)) & F_MASK);
        wl[mslot] = make_uint4(start, start + c, (unsigned)k, rank);
    }
}

// ---------------------------------------------------------------- fused per-point pass + pad fill (r8 geometry)
// Point blocks: 8 points per wave (8 lanes/point, 4 f4 slots per lane).
//   Chain starts with the COMPACT 4B rank32[key] lookup; only multi
//   threads (43%) additionally read the 8B pairs[key] for `start`.
// Pad blocks (appended): stream zero rows [nU, n).
__global__ void __launch_bounds__(256)
pointscatter_pad_kernel(const float* __restrict__ feat, const unsigned* __restrict__ keys,
                        const unsigned* __restrict__ rank32,
                        const unsigned long long* __restrict__ pairs,
                        const unsigned long long* __restrict__ bsums,
                        unsigned* __restrict__ cnt, unsigned* __restrict__ pids,
                        float* __restrict__ outF, float* __restrict__ outI,
                        const unsigned long long* __restrict__ total,
                        int n, int pointBlocks) {
    int lane = threadIdx.x & 63;
    int wid  = threadIdx.x >> 6;
    int e    = lane >> 3;                 // point / row within wave's 8
    int sub  = lane & 7;                  // f4 slots sub, sub+8, sub+16, sub+24
    if ((int)blockIdx.x < pointBlocks) {
        long p = (long)blockIdx.x * 32 + wid * 8 + e;
        if (p >= n) return;
        unsigned key = keys[p];
        unsigned r32 = rank32[key];
        if (r32 >> 31) {                  // singleton: copy own row to out[rank]
            unsigned rank = r32 & 0x7FFFFFFFu;
            const f4* src = (const f4*)(feat + (size_t)p * C_DIM);
            f4*       dst = (f4*)(outF + (size_t)rank * C_DIM);
            f4 v0 = __builtin_nontemporal_load(src + sub);
            f4 v1 = __builtin_nontemporal_load(src + sub + 8);
            f4 v2 = __builtin_nontemporal_load(src + sub + 16);
            f4 v3 = __builtin_nontemporal_load(src + sub + 24);
            __builtin_nontemporal_store(v0, dst + sub);
            __builtin_nontemporal_store(v1, dst + sub + 8);
            __builtin_nontemporal_store(v2, dst + sub + 16);
            __builtin_nontemporal_store(v3, dst + sub + 24);
        } else if (sub == 0) {            // multi: scatter pid (cnt doubles as cursor)
            unsigned long long Pc = pairs[key] + bsums[key >> 11];   // flag==0 for multi
            unsigned start = (unsigned)(Pc & F_MASK);
            unsigned off = atomicSub(&cnt[key], 1u) - 1u;    // c-1, ..., 0
            pids[start + off] = (unsigned)p;
        }
    } else {
        // pad rows [nU, n): zeros + (-1, 467, 467)
        unsigned long long tot = *total;
        long nU = (long)((tot >> F_BITS) & F_MASK);
        long base   = nU + (long)((int)blockIdx.x - pointBlocks) * 32 + wid * 8 + e;
        long stride = (long)(gridDim.x - pointBlocks) * 32;
        f4 z = (f4)(0.f);
        for (long r = base; r < n; r += stride) {
            f4* dst = (f4*)(outF + (size_t)r * C_DIM);
            __builtin_nontemporal_store(z, dst + sub);
            __builtin_nontemporal_store(z, dst + sub + 8);
            __builtin_nontemporal_store(z, dst + sub + 16);
            __builtin_nontemporal_store(z, dst + sub + 24);
            if (sub == 0) {
                outI[(size_t)r * 3 + 0] = -1.0f;
                outI[(size_t)r * 3 + 1] = 467.0f;   // (-1 % YX) // X per numpy floor-mod
                outI[(size_t)r * 3 + 2] = 467.0f;
            }
        }
    }
}

// ---------------------------------------------------------------- multi gather+sum: 4 rows/wave, paired-pid unroll (r8-exact)
__global__ void __launch_bounds__(256)
multi_kernel(const float* __restrict__ feat, const unsigned* __restrict__ pointIds,
             const uint4* __restrict__ wl,
             const unsigned long long* __restrict__ total,
             float* __restrict__ outF) {
    int lane = threadIdx.x & 63;
    int wid  = threadIdx.x >> 6;
    int rq   = lane >> 4;                 // row within wave's 4
    int sub  = lane & 15;                 // f4 slots sub, sub+16
    long m = (long)(((*total) >> (2 * F_BITS)) & F_MASK);
    long base   = (long)blockIdx.x * 16 + wid * 4 + rq;
    long stride = (long)gridDim.x * 16;
    for (long r = base; r < m; r += stride) {
        uint4 d = wl[r];
        f4 a0 = (f4)(0.f);
        f4 a1 = (f4)(0.f);
        unsigned j = d.x, e = d.y;
        for (; j + 1 < e; j += 2) {       // paired: 4 independent row-half loads in flight
            unsigned p0 = pointIds[j];
            unsigned p1 = pointIds[j + 1];
            const f4* s0 = (const f4*)(feat + (size_t)p0 * C_DIM);
            const f4* s1 = (const f4*)(feat + (size_t)p1 * C_DIM);
            f4 v00 = __builtin_nontemporal_load(s0 + sub);
            f4 v01 = __builtin_nontemporal_load(s0 + sub + 16);
            f4 v10 = __builtin_nontemporal_load(s1 + sub);
            f4 v11 = __builtin_nontemporal_load(s1 + sub + 16);
            a0 += v00 + v10;
            a1 += v01 + v11;
        }
        if (j < e) {
            unsigned p0 = pointIds[j];
            const f4* s0 = (const f4*)(feat + (size_t)p0 * C_DIM);
            f4 v00 = __builtin_nontemporal_load(s0 + sub);
            f4 v01 = __builtin_nontemporal_load(s0 + sub + 16);
            a0 += v00;
            a1 += v01;
        }
        f4* dst = (f4*)(outF + (size_t)d.w * C_DIM);
        __builtin_nontemporal_store(a0, dst + sub);
        __builtin_nontemporal_store(a1, dst + sub + 16);
    }
}

extern "C" void kernel_launch(void* const* d_in, const int* in_sizes, int n_in,
                              void* d_out, int out_size, void* d_ws, size_t ws_size,
                              hipStream_t stream) {
    const float* feat = (const float*)d_in[0];
    const int*   idx  = (const int*)d_in[1];
    const int n = in_sizes[0] / C_DIM;   // 1,000,000
    const int K = KSPACE;

    // workspace layout (256B aligned slices)
    char* ws = (char*)d_ws;
    size_t off = 0;
    auto take = [&](size_t bytes) {
        size_t cur = off;
        off = (off + bytes + 255) & ~(size_t)255;
        return cur;
    };
    size_t o_cnt    = take((size_t)K * 4);        // count per key (reused as scatter cursor)
    size_t o_rank32 = take((size_t)K * 4);        // compact rank | single<<31 per key
    size_t o_keys   = take((size_t)n * 4);        // cached keys per point
    size_t o_pairs  = take((size_t)K * 8);        // packed scan prefixes + singleton flag
    size_t o_bsums  = take((size_t)(NBLK + 1) * 8);
    size_t o_pids   = take((size_t)n * 4);        // point ids (multi buckets only)
    size_t o_wl     = take((size_t)(n / 2 + 1) * 16);  // worklist {start,end,key,rank}

    unsigned*           cnt    = (unsigned*)(ws + o_cnt);
    unsigned*           rank32 = (unsigned*)(ws + o_rank32);
    unsigned*           keys   = (unsigned*)(ws + o_keys);
    unsigned long long* pairs  = (unsigned long long*)(ws + o_pairs);
    unsigned long long* bsums  = (unsigned long long*)(ws + o_bsums);
    unsigned*           pids   = (unsigned*)(ws + o_pids);
    uint4*              wl     = (uint4*)(ws + o_wl);

    float* outF = (float*)d_out;
    float* outI = outF + (size_t)n * C_DIM;

    // 1. zero cnt (fill-rate)
    hipMemsetAsync(cnt, 0, (size_t)K * 4, stream);
    // 2. histogram + cache keys
    hist_kernel<<<(n + 255) / 256, 256, 0, stream>>>(idx, cnt, keys, n);
    // 3-4. two-level exclusive scan of packed (count|unique|multi)
    scan1_kernel<<<NBLK, WG, 0, stream>>>(cnt, pairs, bsums, K);
    scan2_kernel<<<1, 1024, 0, stream>>>(bsums, NBLK);
    // 5. per-key pass: sequential outI + multi worklist + compact rank32
    uniq_kernel<<<(K + 255) / 256, 256, 0, stream>>>(cnt, pairs, bsums, wl, rank32, outI, K);
    // 6. fused per-point pass (singleton copy / pid scatter) + pad fill
    {
        int pointBlocks = (n + 31) / 32;
        pointscatter_pad_kernel<<<pointBlocks + PAD_BLOCKS, 256, 0, stream>>>(
            feat, keys, rank32, pairs, bsums, cnt, pids, outF, outI, bsums + NBLK,
            n, pointBlocks);
    }
    // 7. multi gather+sum
    multi_kernel<<<4096, 256, 0, stream>>>(feat, pids, wl, bsums + NBLK, outF);
}